// Round 11
// baseline (100.834 us; speedup 1.0000x reference)
//
#include <hip/hip_runtime.h>
#include <math.h>

#define N_NEU 256
#define D_DIM 32
#define KFD   16
#define KN    50
#define B_SZ  512
#define UINF  128
#define GAMMA 0.1f
#define DT    0.05f
#define NSTEP 20

#define TBL_K   4096
#define TBL_LO  (-64.0f)
#define TBL_IDL 32.0f          // 1/Delta ; Delta = 1/32, range [-64, +64)

// pre_kernel grid layout: 128 rows of u per uproj block (2 m-tiles per wave)
#define UPROJ_BLKS (B_SZ * N_NEU / 128)  // 1024
#define TOPK_BLKS  N_NEU                 // 256
#define TBL_BLKS   (TBL_K * 32 / 256)    // 512

typedef __attribute__((ext_vector_type(8))) short bf16x8;
typedef __attribute__((ext_vector_type(4))) float f32x4;

__device__ __forceinline__ unsigned short f2bf(float f) {
    unsigned u = __float_as_uint(f);
    u += 0x7FFFu + ((u >> 16) & 1u);     // round-to-nearest-even
    return (unsigned short)(u >> 16);
}
__device__ __forceinline__ float bf_lo(unsigned q) { return __uint_as_float(q << 16); }
__device__ __forceinline__ float bf_hi(unsigned q) { return __uint_as_float(q & 0xFFFF0000u); }

__device__ __forceinline__ bf16x8 pack8(float4 a0, float4 a1) {
    bf16x8 f;
    f[0] = (short)f2bf(a0.x); f[1] = (short)f2bf(a0.y);
    f[2] = (short)f2bf(a0.z); f[3] = (short)f2bf(a0.w);
    f[4] = (short)f2bf(a1.x); f[5] = (short)f2bf(a1.y);
    f[6] = (short)f2bf(a1.z); f[7] = (short)f2bf(a1.w);
    return f;
}

// ---------------------------------------------------------------------------
// Fused pre-kernel: [0,1024) uproj-MFMA | [1024,1280) topk | [1280,1792) tbl.
// uproj: 2 m-tiles/wave (32 rows). ALL 16 w_in-loads then ALL 16 u-loads are
// issued as named float4 registers BEFORE any consumer — r10 showed the
// compiler's occupancy heuristic (VGPR=76 both with and without a rotating-
// buffer pipeline) re-serialized prefetches; launch_bounds(256,2) licenses
// 256 VGPR so the full load batch stays in flight (~16/wave, BDP-covering).
// ---------------------------------------------------------------------------
__global__ __launch_bounds__(256, 2) void pre_kernel(const float* __restrict__ u,
                                                     const float* __restrict__ w_in,
                                                     const float* __restrict__ b_in,
                                                     const float* __restrict__ bias,
                                                     const float* __restrict__ sig_b2,
                                                     const float* __restrict__ features,
                                                     const float* __restrict__ sig_w1,
                                                     const float* __restrict__ sig_b1,
                                                     const float* __restrict__ sig_w2,
                                                     int* __restrict__ idxT,
                                                     float* __restrict__ vals2T,
                                                     unsigned int* __restrict__ tbl,
                                                     float* __restrict__ cdt) {
    __shared__ float fsh[N_NEU][KFD + 1];
    __shared__ float sim_sh[N_NEU];

    const int bid = blockIdx.x;

    if (bid < UPROJ_BLKS) {
        const int  wave = threadIdx.x >> 6;
        const int  lane = threadIdx.x & 63;
        const long m0   = (long)bid * 128 + (long)wave * 32;
        const int  row  = lane & 15;
        const int  kg   = lane >> 4;

        // ---- issue ALL w_in loads (16 float4) ----
        float4 wf[16];
#pragma unroll
        for (int q = 0; q < 16; ++q) {
            const int dt_ = q >> 3, kk = (q >> 1) & 3, hf = q & 1;
            wf[q] = *reinterpret_cast<const float4*>(
                w_in + (dt_ * 16 + row) * UINF + kk * 32 + kg * 8 + hf * 4);
        }

        // ---- issue ALL u loads (16 float4) ----
        float4 L[16];
#pragma unroll
        for (int t4 = 0; t4 < 2; ++t4) {
#pragma unroll
            for (int kk = 0; kk < 4; ++kk) {
                const float* up = u + (m0 + t4 * 16 + row) * UINF + kk * 32 + kg * 8;
                L[(t4 * 4 + kk) * 2 + 0] = *reinterpret_cast<const float4*>(up);
                L[(t4 * 4 + kk) * 2 + 1] = *reinterpret_cast<const float4*>(up + 4);
            }
        }

        // ---- convert w_in (waits only on wf; u loads keep flying) ----
        bf16x8 bfrag[2][4];
#pragma unroll
        for (int dt_ = 0; dt_ < 2; ++dt_)
#pragma unroll
            for (int kk = 0; kk < 4; ++kk)
                bfrag[dt_][kk] = pack8(wf[dt_ * 8 + kk * 2], wf[dt_ * 8 + kk * 2 + 1]);

        // ---- consume ----
        f32x4 acc[2][2];
#pragma unroll
        for (int t4 = 0; t4 < 2; ++t4) {
            acc[t4][0] = (f32x4){0.f, 0.f, 0.f, 0.f};
            acc[t4][1] = (f32x4){0.f, 0.f, 0.f, 0.f};
        }
#pragma unroll
        for (int t4 = 0; t4 < 2; ++t4) {
#pragma unroll
            for (int kk = 0; kk < 4; ++kk) {
                const int ui = (t4 * 4 + kk) * 2;
                const bf16x8 af = pack8(L[ui], L[ui + 1]);
                acc[t4][0] = __builtin_amdgcn_mfma_f32_16x16x32_bf16(af, bfrag[0][kk], acc[t4][0], 0, 0, 0);
                acc[t4][1] = __builtin_amdgcn_mfma_f32_16x16x32_bf16(af, bfrag[1][kk], acc[t4][1], 0, 0, 0);
            }
        }

        const int   d0   = row;
        const int   d1   = 16 + row;
        const float add0 = b_in[d0] + sig_b2[d0];
        const float add1 = b_in[d1] + sig_b2[d1];
#pragma unroll
        for (int t4 = 0; t4 < 2; ++t4) {
#pragma unroll
            for (int r = 0; r < 4; ++r) {
                const long m  = m0 + t4 * 16 + kg * 4 + r;
                const int  nn = (int)(m & (N_NEU - 1));
                cdt[m * D_DIM + d0] = DT * (acc[t4][0][r] + add0 + bias[nn * D_DIM + d0]);
                cdt[m * D_DIM + d1] = DT * (acc[t4][1][r] + add1 + bias[nn * D_DIM + d1]);
            }
        }
    } else if (bid < UPROJ_BLKS + TOPK_BLKS) {
        // ---- topk ----
        const int n = bid - UPROJ_BLKS;
        const int j = threadIdx.x;

        float v[KFD];
        float s = 0.f;
#pragma unroll
        for (int d = 0; d < KFD; ++d) { v[d] = features[j * KFD + d]; s = fmaf(v[d], v[d], s); }
        const float nrm = sqrtf(s);
#pragma unroll
        for (int d = 0; d < KFD; ++d) fsh[j][d] = v[d] / nrm;
        __syncthreads();

        float dot = 0.f;
#pragma unroll
        for (int d = 0; d < KFD; ++d) dot = fmaf(fsh[n][d], fsh[j][d], dot);
        sim_sh[j] = dot;
        __syncthreads();

        if (j < 64) {
            float l0 = sim_sh[j];
            float l1 = sim_sh[j + 64];
            float l2 = sim_sh[j + 128];
            float l3 = sim_sh[j + 192];
            for (int k = 0; k < KN; ++k) {
                float bv = l0; int bi = j;
                if (l1 > bv) { bv = l1; bi = j + 64; }
                if (l2 > bv) { bv = l2; bi = j + 128; }
                if (l3 > bv) { bv = l3; bi = j + 192; }
                for (int off = 32; off > 0; off >>= 1) {
                    float ov = __shfl_xor(bv, off, 64);
                    int   oi = __shfl_xor(bi, off, 64);
                    if (ov > bv || (ov == bv && oi < bi)) { bv = ov; bi = oi; }
                }
                if (j == 0) {
                    const int s_ = k / 14;
                    const int r_ = k - 14 * s_;
                    vals2T[((r_ >> 1) * 1024 + n * 4 + s_) * 2 + (r_ & 1)] = bv;
                    idxT[k * N_NEU + n] = bi;
                }
                if ((bi & 63) == j) {
                    const int q = bi >> 6;
                    if      (q == 0) l0 = -INFINITY;
                    else if (q == 1) l1 = -INFINITY;
                    else if (q == 2) l2 = -INFINITY;
                    else             l3 = -INFINITY;
                }
            }
            if (j == 0) {   // zero-pad k = 50..55 (subthread 3, r = 8..13)
#pragma unroll
                for (int k = 50; k < 56; ++k) {
                    const int r_ = k - 42;
                    vals2T[((r_ >> 1) * 1024 + n * 4 + 3) * 2 + (r_ & 1)] = 0.f;
                }
            }
        }
    } else {
        // ---- mlp table ----
        const int gid = (bid - UPROJ_BLKS - TOPK_BLKS) * 256 + threadIdx.x;  // k*32+d
        const int k = gid >> 5, d = gid & 31;
        const float s0 = TBL_LO + (float)k / TBL_IDL;
        const float s1 = s0 + 1.0f / TBL_IDL;
        float g0 = 0.f, g1 = 0.f;
#pragma unroll
        for (int j = 0; j < 16; ++j) {
            const float w1 = sig_w1[j], b1 = sig_b1[j], w2 = sig_w2[d * 16 + j];
            const float h0 = fmaf(s0, w1, b1);
            const float h1 = fmaf(s1, w1, b1);
            const float e0 = 0.5f * h0 * (1.0f + erff(h0 * 0.70710678118654752f));
            const float e1 = 0.5f * h1 * (1.0f + erff(h1 * 0.70710678118654752f));
            g0 = fmaf(e0, w2, g0);
            g1 = fmaf(e1, w2, g1);
        }
        g0 *= DT; g1 *= DT;
        tbl[gid] = (unsigned int)f2bf(g0) | ((unsigned int)f2bf(g1 - g0) << 16);
    }
}

// ---------------------------------------------------------------------------
// Steps kernel v11: r10 structure, but vals live in 7 float2 REGISTERS
// (step-invariant per thread; LDS staging was pure overhead). LDS per step
// drops to the 14 packed gathers only (a_sh = 2 KB total).
// ---------------------------------------------------------------------------
__global__ __launch_bounds__(1024) void steps_kernel(const float* __restrict__ cdt,
                                                     const int* __restrict__ idxT,
                                                     const float* __restrict__ vals2T,
                                                     const unsigned int* __restrict__ tbl,
                                                     float* __restrict__ out) {
    __shared__ unsigned int a_sh[2][N_NEU];        // packed 2-batch bf16

    const int t  = threadIdx.x;
    const int n  = t >> 2;
    const int s  = t & 3;
    const int bb = s >> 1;
    const int h  = s & 1;
    const int b  = blockIdx.x * 2 + bb;

    // step-invariant per-thread vals (coalesced global read, once)
    const float2* v2g = reinterpret_cast<const float2*>(vals2T);
    float2 vv[7];
#pragma unroll
    for (int jj = 0; jj < 7; ++jj) vv[jj] = v2g[jj * 1024 + t];

    // step-invariant gather pointers into a_sh[0][.] (buf 1 = +N_NEU elements)
    const unsigned int* gp[14];
#pragma unroll
    for (int j = 0; j < 14; ++j) {
        const int k = s * 14 + j;
        const int ii = (k < KN) ? idxT[k * N_NEU + n] : 0;
        gp[j] = &a_sh[0][ii];
    }

    float x[16], ccdt[16];
    const float4* cp4 = reinterpret_cast<const float4*>(cdt + ((size_t)b * N_NEU + n) * D_DIM + h * 16);
#pragma unroll
    for (int i = 0; i < 4; ++i) {
        const float4 cv = cp4[i];
        ccdt[4 * i + 0] = cv.x; ccdt[4 * i + 1] = cv.y;
        ccdt[4 * i + 2] = cv.z; ccdt[4 * i + 3] = cv.w;
    }
#pragma unroll
    for (int d = 0; d < 16; ++d) x[d] = 0.f;

    const float K1 = 1.0f - DT * GAMMA;   // 0.995

#define STEP_BODY(BUF)                                                          \
    {                                                                           \
        float nh0 = 0.f, nh1 = 0.f;                                             \
        _Pragma("unroll")                                                       \
        for (int d = 0; d < 16; d += 2) {                                       \
            nh0 = fmaf(x[d], x[d], nh0);                                        \
            nh1 = fmaf(x[d + 1], x[d + 1], nh1);                                \
        }                                                                       \
        const float nh = nh0 + nh1;                                             \
        const float nfull = nh + __shfl_xor(nh, 1, 64) + 1e-12f;                \
        const float z = sqrtf(nfull);                                           \
        const float a = 1.0f - 2.0f / (__expf(2.0f * z) + 1.0f);                \
        const float ao = __shfl_xor(a, 2, 64);                                  \
        if (s == 0) a_sh[BUF][n] = (unsigned int)f2bf(a) | ((unsigned int)f2bf(ao) << 16); \
        _Pragma("unroll")                                                       \
        for (int d = 0; d < 16; ++d) x[d] = fmaf(K1, x[d], ccdt[d]);            \
        __syncthreads();                                                        \
        float sA0 = 0.f, sA1 = 0.f, sB0 = 0.f, sB1 = 0.f;                       \
        _Pragma("unroll")                                                       \
        for (int jj = 0; jj < 7; ++jj) {                                        \
            const unsigned int p0 = gp[2 * jj][(BUF) * N_NEU];                  \
            const unsigned int p1 = gp[2 * jj + 1][(BUF) * N_NEU];              \
            sA0 = fmaf(bf_lo(p0), vv[jj].x, sA0);                               \
            sB0 = fmaf(bf_hi(p0), vv[jj].x, sB0);                               \
            sA1 = fmaf(bf_lo(p1), vv[jj].y, sA1);                               \
            sB1 = fmaf(bf_hi(p1), vv[jj].y, sB1);                               \
        }                                                                       \
        float sA = sA0 + sA1;                                                   \
        float sB = sB0 + sB1;                                                   \
        sA += __shfl_xor(sA, 1, 64); sA += __shfl_xor(sA, 2, 64);               \
        sB += __shfl_xor(sB, 1, 64); sB += __shfl_xor(sB, 2, 64);               \
        const float syn = bb ? sB : sA;                                         \
        const float uu = fmaf(syn, TBL_IDL, -TBL_LO * TBL_IDL);                 \
        int i = (int)uu;                                                        \
        i = (i < 0) ? 0 : (i > TBL_K - 2 ? TBL_K - 2 : i);                      \
        const float tf = uu - (float)i;                                         \
        const uint4* rp = reinterpret_cast<const uint4*>(tbl + (size_t)i * 32 + h * 16); \
        _Pragma("unroll")                                                       \
        for (int c = 0; c < 4; ++c) {                                           \
            const uint4 q = rp[c];                                              \
            x[4 * c + 0] = fmaf(tf, bf_hi(q.x), x[4 * c + 0] + bf_lo(q.x));     \
            x[4 * c + 1] = fmaf(tf, bf_hi(q.y), x[4 * c + 1] + bf_lo(q.y));     \
            x[4 * c + 2] = fmaf(tf, bf_hi(q.z), x[4 * c + 2] + bf_lo(q.z));     \
            x[4 * c + 3] = fmaf(tf, bf_hi(q.w), x[4 * c + 3] + bf_lo(q.w));     \
        }                                                                       \
    }

    for (int it = 0; it < NSTEP / 2; ++it) {
        STEP_BODY(0);
        STEP_BODY(1);
    }
#undef STEP_BODY

    float4* op4 = reinterpret_cast<float4*>(out + ((size_t)b * N_NEU + n) * D_DIM + h * 16);
#pragma unroll
    for (int i = 0; i < 4; ++i)
        op4[i] = make_float4(x[4 * i + 0], x[4 * i + 1], x[4 * i + 2], x[4 * i + 3]);
}

extern "C" void kernel_launch(void* const* d_in, const int* in_sizes, int n_in,
                              void* d_out, int out_size, void* d_ws, size_t ws_size,
                              hipStream_t stream) {
    const float* u        = (const float*)d_in[0];
    const float* features = (const float*)d_in[1];
    const float* bias     = (const float*)d_in[2];
    const float* w_in     = (const float*)d_in[3];
    const float* b_in     = (const float*)d_in[4];
    const float* sig_w1   = (const float*)d_in[5];
    const float* sig_b1   = (const float*)d_in[6];
    const float* sig_w2   = (const float*)d_in[7];
    const float* sig_b2   = (const float*)d_in[8];
    float* out = (float*)d_out;

    char*         ws     = (char*)d_ws;
    int*          idxT   = (int*)ws;                      // 51200 B
    float*        vals2T = (float*)(ws + 51200);          // 57344 B
    unsigned int* tbl    = (unsigned int*)(ws + 110592);  // 512 KiB
    float*        cdt    = (float*)(ws + 110592 + 524288);// 16 MiB

    hipLaunchKernelGGL(pre_kernel, dim3(UPROJ_BLKS + TOPK_BLKS + TBL_BLKS), dim3(256), 0, stream,
                       u, w_in, b_in, bias, sig_b2, features, sig_w1, sig_b1, sig_w2,
                       idxT, vals2T, tbl, cdt);
    hipLaunchKernelGGL(steps_kernel, dim3(B_SZ / 2), dim3(1024), 0, stream,
                       cdt, idxT, vals2T, tbl, out);
}

// Round 12
// 94.989 us; speedup vs baseline: 1.0615x; 1.0615x over previous
//
#include <hip/hip_runtime.h>
#include <math.h>

#define N_NEU 256
#define D_DIM 32
#define KFD   16
#define KN    50
#define B_SZ  512
#define UINF  128
#define GAMMA 0.1f
#define DT    0.05f
#define NSTEP 20

#define TBL_K   4096
#define TBL_LO  (-64.0f)
#define TBL_IDL 32.0f          // 1/Delta ; Delta = 1/32, range [-64, +64)

#define TOPK_BLKS  N_NEU                 // 256
#define TBL_BLKS   (TBL_K * 32 / 256)    // 512

typedef __attribute__((ext_vector_type(8))) short bf16x8;
typedef __attribute__((ext_vector_type(4))) float f32x4;

__device__ __forceinline__ unsigned short f2bf(float f) {
    unsigned u = __float_as_uint(f);
    u += 0x7FFFu + ((u >> 16) & 1u);     // round-to-nearest-even
    return (unsigned short)(u >> 16);
}
__device__ __forceinline__ float bf_lo(unsigned q) { return __uint_as_float(q << 16); }
__device__ __forceinline__ float bf_hi(unsigned q) { return __uint_as_float(q & 0xFFFF0000u); }

__device__ __forceinline__ bf16x8 pack8(float4 a0, float4 a1) {
    bf16x8 f;
    f[0] = (short)f2bf(a0.x); f[1] = (short)f2bf(a0.y);
    f[2] = (short)f2bf(a0.z); f[3] = (short)f2bf(a0.w);
    f[4] = (short)f2bf(a1.x); f[5] = (short)f2bf(a1.y);
    f[6] = (short)f2bf(a1.z); f[7] = (short)f2bf(a1.w);
    return f;
}

// ---------------------------------------------------------------------------
// Kernel A: topk [0,256) + mlp table [256,768). uproj has moved into the
// steps kernel (rounds 9-11: the standalone uproj was latency-bound; the
// compiler re-serializes register prefetches regardless of source phrasing).
// ---------------------------------------------------------------------------
__global__ __launch_bounds__(256) void pre_kernel(const float* __restrict__ features,
                                                  const float* __restrict__ sig_w1,
                                                  const float* __restrict__ sig_b1,
                                                  const float* __restrict__ sig_w2,
                                                  int* __restrict__ idxT,
                                                  float* __restrict__ vals2T,
                                                  unsigned int* __restrict__ tbl) {
    __shared__ float fsh[N_NEU][KFD + 1];
    __shared__ float sim_sh[N_NEU];

    const int bid = blockIdx.x;

    if (bid < TOPK_BLKS) {
        // ---- topk ----
        const int n = bid;
        const int j = threadIdx.x;

        float v[KFD];
        float s = 0.f;
#pragma unroll
        for (int d = 0; d < KFD; ++d) { v[d] = features[j * KFD + d]; s = fmaf(v[d], v[d], s); }
        const float nrm = sqrtf(s);
#pragma unroll
        for (int d = 0; d < KFD; ++d) fsh[j][d] = v[d] / nrm;
        __syncthreads();

        float dot = 0.f;
#pragma unroll
        for (int d = 0; d < KFD; ++d) dot = fmaf(fsh[n][d], fsh[j][d], dot);
        sim_sh[j] = dot;
        __syncthreads();

        if (j < 64) {
            float l0 = sim_sh[j];
            float l1 = sim_sh[j + 64];
            float l2 = sim_sh[j + 128];
            float l3 = sim_sh[j + 192];
            for (int k = 0; k < KN; ++k) {
                float bv = l0; int bi = j;
                if (l1 > bv) { bv = l1; bi = j + 64; }
                if (l2 > bv) { bv = l2; bi = j + 128; }
                if (l3 > bv) { bv = l3; bi = j + 192; }
                for (int off = 32; off > 0; off >>= 1) {
                    float ov = __shfl_xor(bv, off, 64);
                    int   oi = __shfl_xor(bi, off, 64);
                    if (ov > bv || (ov == bv && oi < bi)) { bv = ov; bi = oi; }
                }
                if (j == 0) {
                    const int s_ = k / 14;
                    const int r_ = k - 14 * s_;
                    vals2T[((r_ >> 1) * 1024 + n * 4 + s_) * 2 + (r_ & 1)] = bv;
                    idxT[k * N_NEU + n] = bi;
                }
                if ((bi & 63) == j) {
                    const int q = bi >> 6;
                    if      (q == 0) l0 = -INFINITY;
                    else if (q == 1) l1 = -INFINITY;
                    else if (q == 2) l2 = -INFINITY;
                    else             l3 = -INFINITY;
                }
            }
            if (j == 0) {   // zero-pad k = 50..55 (subthread 3, r = 8..13)
#pragma unroll
                for (int k = 50; k < 56; ++k) {
                    const int r_ = k - 42;
                    vals2T[((r_ >> 1) * 1024 + n * 4 + 3) * 2 + (r_ & 1)] = 0.f;
                }
            }
        }
    } else {
        // ---- mlp table ----
        const int gid = (bid - TOPK_BLKS) * 256 + threadIdx.x;  // k*32+d
        const int k = gid >> 5, d = gid & 31;
        const float s0 = TBL_LO + (float)k / TBL_IDL;
        const float s1 = s0 + 1.0f / TBL_IDL;
        float g0 = 0.f, g1 = 0.f;
#pragma unroll
        for (int j = 0; j < 16; ++j) {
            const float w1 = sig_w1[j], b1 = sig_b1[j], w2 = sig_w2[d * 16 + j];
            const float h0 = fmaf(s0, w1, b1);
            const float h1 = fmaf(s1, w1, b1);
            const float e0 = 0.5f * h0 * (1.0f + erff(h0 * 0.70710678118654752f));
            const float e1 = 0.5f * h1 * (1.0f + erff(h1 * 0.70710678118654752f));
            g0 = fmaf(e0, w2, g0);
            g1 = fmaf(e1, w2, g1);
        }
        g0 *= DT; g1 *= DT;
        tbl[gid] = (unsigned int)f2bf(g0) | ((unsigned int)f2bf(g1 - g0) << 16);
    }
}

// ---------------------------------------------------------------------------
// Kernel B: fused uproj-GEMM + 20-step recurrence. Grid 256 x 1024 threads.
// Phase 0 (GEMM): w_in staged to LDS as bf16 (padded rows, ~8.7 KB); each of
// the 16 waves MFMAs 32 u-rows of its batch (16 float4 loads/wave — with 16
// co-resident waves the per-CU in-flight bytes >> BDP, so HBM saturates by
// TLP, which the r9-r11 standalone kernel could never achieve). Results
// (DT-scaled, +b_in+bias+sig_b2) go to cdt_sh (stride 36 floats = pad to
// break the 32-way d-column bank conflict), then each thread pulls its
// ccdt[16]. Eliminates: 63-us pre-uproj, 16 MB cdt write + 16 MB read.
// Phase 1: identical to round-11 steps (packed 2-batch bf16 a, register vals,
// step-invariant gather pointers, one barrier/step).
// ---------------------------------------------------------------------------
__global__ __launch_bounds__(1024) void steps_kernel(const float* __restrict__ u,
                                                     const float* __restrict__ w_in,
                                                     const float* __restrict__ b_in,
                                                     const float* __restrict__ bias,
                                                     const float* __restrict__ sig_b2,
                                                     const int* __restrict__ idxT,
                                                     const float* __restrict__ vals2T,
                                                     const unsigned int* __restrict__ tbl,
                                                     float* __restrict__ out) {
    __shared__ unsigned short wsh[32 * 136];       // bf16 w_in, row stride 136 (pad 8)
    __shared__ float cdt_sh[2 * 256 * 36];         // 73728 B, row stride 36 (pad 4)
    __shared__ unsigned int a_sh[2 * N_NEU];       // packed 2-batch bf16

    const int t = threadIdx.x;

    // ---- phase 0a: stage w_in -> LDS bf16 ----
    {
        const float4 w4 = reinterpret_cast<const float4*>(w_in)[t];
        const int d = t >> 5, k0 = (t & 31) * 4;
        unsigned short* wp = &wsh[d * 136 + k0];
        wp[0] = f2bf(w4.x); wp[1] = f2bf(w4.y); wp[2] = f2bf(w4.z); wp[3] = f2bf(w4.w);
    }
    __syncthreads();

    // ---- phase 0b: per-wave 32-row GEMM ----
    {
        const int wave = t >> 6;
        const int lane = t & 63;
        const int row  = lane & 15;
        const int kg   = lane >> 4;
        const int bb0  = wave >> 3;                    // which batch of the pair
        const int wrow = (wave & 7) * 32;              // first neuron row of wave
        const long bB  = (long)blockIdx.x * 2 + bb0;

        bf16x8 bfrag[2][4];
#pragma unroll
        for (int dt_ = 0; dt_ < 2; ++dt_)
#pragma unroll
            for (int kk = 0; kk < 4; ++kk)
                bfrag[dt_][kk] = *reinterpret_cast<const bf16x8*>(
                    &wsh[(dt_ * 16 + row) * 136 + kk * 32 + kg * 8]);

#pragma unroll
        for (int t4 = 0; t4 < 2; ++t4) {
            const float* ub = u + (bB * N_NEU + wrow + t4 * 16 + row) * UINF + kg * 8;
            float4 L[8];
#pragma unroll
            for (int kk = 0; kk < 4; ++kk) {
                L[kk * 2 + 0] = *reinterpret_cast<const float4*>(ub + kk * 32);
                L[kk * 2 + 1] = *reinterpret_cast<const float4*>(ub + kk * 32 + 4);
            }
            f32x4 a0 = {0.f, 0.f, 0.f, 0.f};
            f32x4 a1 = {0.f, 0.f, 0.f, 0.f};
#pragma unroll
            for (int kk = 0; kk < 4; ++kk) {
                const bf16x8 af = pack8(L[kk * 2], L[kk * 2 + 1]);
                a0 = __builtin_amdgcn_mfma_f32_16x16x32_bf16(af, bfrag[0][kk], a0, 0, 0, 0);
                a1 = __builtin_amdgcn_mfma_f32_16x16x32_bf16(af, bfrag[1][kk], a1, 0, 0, 0);
            }
            const int   d0   = row;
            const int   d1   = 16 + row;
            const float add0 = b_in[d0] + sig_b2[d0];
            const float add1 = b_in[d1] + sig_b2[d1];
#pragma unroll
            for (int r = 0; r < 4; ++r) {
                const int nl = wrow + t4 * 16 + kg * 4 + r;
                cdt_sh[bb0 * 9216 + nl * 36 + d0] = DT * (a0[r] + add0 + bias[nl * D_DIM + d0]);
                cdt_sh[bb0 * 9216 + nl * 36 + d1] = DT * (a1[r] + add1 + bias[nl * D_DIM + d1]);
            }
        }
    }
    __syncthreads();

    // ---- phase 0c: redistribute to per-thread ccdt regs ----
    const int n  = t >> 2;
    const int s  = t & 3;
    const int bb = s >> 1;
    const int h  = s & 1;
    const int b  = blockIdx.x * 2 + bb;

    float ccdt[16];
    {
        const float* cbase = &cdt_sh[bb * 9216 + n * 36 + h * 16];
#pragma unroll
        for (int i = 0; i < 4; ++i) {
            const float4 cv = *reinterpret_cast<const float4*>(cbase + i * 4);
            ccdt[4 * i + 0] = cv.x; ccdt[4 * i + 1] = cv.y;
            ccdt[4 * i + 2] = cv.z; ccdt[4 * i + 3] = cv.w;
        }
    }

    // ---- step-invariant per-thread vals + gather pointers ----
    const float2* v2g = reinterpret_cast<const float2*>(vals2T);
    float2 vv[7];
#pragma unroll
    for (int jj = 0; jj < 7; ++jj) vv[jj] = v2g[jj * 1024 + t];

    const unsigned int* gp[14];
#pragma unroll
    for (int j = 0; j < 14; ++j) {
        const int k = s * 14 + j;
        const int ii = (k < KN) ? idxT[k * N_NEU + n] : 0;
        gp[j] = &a_sh[ii];
    }

    float x[16];
#pragma unroll
    for (int d = 0; d < 16; ++d) x[d] = 0.f;

    const float K1 = 1.0f - DT * GAMMA;   // 0.995

#define STEP_BODY(BUF)                                                          \
    {                                                                           \
        float nh0 = 0.f, nh1 = 0.f;                                             \
        _Pragma("unroll")                                                       \
        for (int d = 0; d < 16; d += 2) {                                       \
            nh0 = fmaf(x[d], x[d], nh0);                                        \
            nh1 = fmaf(x[d + 1], x[d + 1], nh1);                                \
        }                                                                       \
        const float nh = nh0 + nh1;                                             \
        const float nfull = nh + __shfl_xor(nh, 1, 64) + 1e-12f;                \
        const float z = sqrtf(nfull);                                           \
        const float a = 1.0f - 2.0f / (__expf(2.0f * z) + 1.0f);                \
        const float ao = __shfl_xor(a, 2, 64);                                  \
        if (s == 0) a_sh[(BUF) * N_NEU + n] = (unsigned int)f2bf(a) | ((unsigned int)f2bf(ao) << 16); \
        _Pragma("unroll")                                                       \
        for (int d = 0; d < 16; ++d) x[d] = fmaf(K1, x[d], ccdt[d]);            \
        __syncthreads();                                                        \
        float sA0 = 0.f, sA1 = 0.f, sB0 = 0.f, sB1 = 0.f;                       \
        _Pragma("unroll")                                                       \
        for (int jj = 0; jj < 7; ++jj) {                                        \
            const unsigned int p0 = gp[2 * jj][(BUF) * N_NEU];                  \
            const unsigned int p1 = gp[2 * jj + 1][(BUF) * N_NEU];              \
            sA0 = fmaf(bf_lo(p0), vv[jj].x, sA0);                               \
            sB0 = fmaf(bf_hi(p0), vv[jj].x, sB0);                               \
            sA1 = fmaf(bf_lo(p1), vv[jj].y, sA1);                               \
            sB1 = fmaf(bf_hi(p1), vv[jj].y, sB1);                               \
        }                                                                       \
        float sA = sA0 + sA1;                                                   \
        float sB = sB0 + sB1;                                                   \
        sA += __shfl_xor(sA, 1, 64); sA += __shfl_xor(sA, 2, 64);               \
        sB += __shfl_xor(sB, 1, 64); sB += __shfl_xor(sB, 2, 64);               \
        const float syn = bb ? sB : sA;                                         \
        const float uu = fmaf(syn, TBL_IDL, -TBL_LO * TBL_IDL);                 \
        int i = (int)uu;                                                        \
        i = (i < 0) ? 0 : (i > TBL_K - 2 ? TBL_K - 2 : i);                      \
        const float tf = uu - (float)i;                                         \
        const uint4* rp = reinterpret_cast<const uint4*>(tbl + (size_t)i * 32 + h * 16); \
        _Pragma("unroll")                                                       \
        for (int c = 0; c < 4; ++c) {                                           \
            const uint4 q = rp[c];                                              \
            x[4 * c + 0] = fmaf(tf, bf_hi(q.x), x[4 * c + 0] + bf_lo(q.x));     \
            x[4 * c + 1] = fmaf(tf, bf_hi(q.y), x[4 * c + 1] + bf_lo(q.y));     \
            x[4 * c + 2] = fmaf(tf, bf_hi(q.z), x[4 * c + 2] + bf_lo(q.z));     \
            x[4 * c + 3] = fmaf(tf, bf_hi(q.w), x[4 * c + 3] + bf_lo(q.w));     \
        }                                                                       \
    }

    for (int it = 0; it < NSTEP / 2; ++it) {
        STEP_BODY(0);
        STEP_BODY(1);
    }
#undef STEP_BODY

    float4* op4 = reinterpret_cast<float4*>(out + ((size_t)b * N_NEU + n) * D_DIM + h * 16);
#pragma unroll
    for (int i = 0; i < 4; ++i)
        op4[i] = make_float4(x[4 * i + 0], x[4 * i + 1], x[4 * i + 2], x[4 * i + 3]);
}

extern "C" void kernel_launch(void* const* d_in, const int* in_sizes, int n_in,
                              void* d_out, int out_size, void* d_ws, size_t ws_size,
                              hipStream_t stream) {
    const float* u        = (const float*)d_in[0];
    const float* features = (const float*)d_in[1];
    const float* bias     = (const float*)d_in[2];
    const float* w_in     = (const float*)d_in[3];
    const float* b_in     = (const float*)d_in[4];
    const float* sig_w1   = (const float*)d_in[5];
    const float* sig_b1   = (const float*)d_in[6];
    const float* sig_w2   = (const float*)d_in[7];
    const float* sig_b2   = (const float*)d_in[8];
    float* out = (float*)d_out;

    char*         ws     = (char*)d_ws;
    int*          idxT   = (int*)ws;                      // 51200 B
    float*        vals2T = (float*)(ws + 51200);          // 57344 B
    unsigned int* tbl    = (unsigned int*)(ws + 110592);  // 512 KiB

    hipLaunchKernelGGL(pre_kernel, dim3(TOPK_BLKS + TBL_BLKS), dim3(256), 0, stream,
                       features, sig_w1, sig_b1, sig_w2, idxT, vals2T, tbl);
    hipLaunchKernelGGL(steps_kernel, dim3(B_SZ / 2), dim3(1024), 0, stream,
                       u, w_in, b_in, bias, sig_b2, idxT, vals2T, tbl, out);
}